// Round 4
// baseline (534.317 us; speedup 1.0000x reference)
//
#include <hip/hip_runtime.h>

// Spatial correlation (cost volume), B=8 C=128 H=W=96, patch 9x9, 3x3 box, pad 1.
// out[b,di,dj,y,x] = sum_{i,j in 0..2} P[b,di,dj,y+i,x+j]
// P[b,di,dj,y',x'] = sum_c q_pad[y',x'] * k_pad[y'+di, x'+dj]   (padded 98x98 grid)
//
// R3: kill the scratch spill for real. R2 still showed VGPR_Count=40 (< the
// 44 live accumulators) -> acc[] lived in scratch; WRITE_SIZE 241MB (~10x the
// output) was L2 scratch spilling to HBM. Root cause: `inline` is only a hint;
// run/do_row were not inlined, so acc had its address taken across a call and
// was forced to memory. Fix: always_inline everything on the acc path and
// never type-pun local arrays (elementwise float4 component assignment only).

#define AI __attribute__((always_inline))

#define BATCH 8
#define CHN   128
#define IMG   96
#define TILE  16    // P-tile edge (padded-grid points) per block
#define OTILE 14    // output-tile edge per block (TILE - 2)
#define NC    8     // channels staged per pass
#define CHALF 64    // channels per block (2-way split)
#define NCB   (CHALF / NC)
#define KT    24    // k-tile edge (TILE + 8)
#define KTP   48    // k-tile col stride (words); 48%32==16 -> consecutive-8-lane
#define QTP   16    //   groups of a b128 read tile all 32 banks exactly once
#define NTHR  512

struct Tiles {
  float qs[NC][TILE][QTP];   //  8192 B (flat-linear staging writes)
  float ks[NC][KT][KTP];     // 36864 B (cols 24..47 unused padding)
};                           // 45056 B total

__device__ AI void stage(const float* __restrict__ qg, const float* __restrict__ kg,
                         Tiles& t, int cbase, int b, int X0, int Y0, int tid) {
  float* qflat = &t.qs[0][0][0];
  for (int idx = tid; idx < NC * TILE * TILE; idx += NTHR) {
    const int c = idx >> 8;
    const int rem = idx & 255;
    const int r = rem >> 4, col = rem & 15;
    const int gy = Y0 + r - 1, gx = X0 + col - 1;
    float v = 0.f;
    if ((unsigned)gy < IMG && (unsigned)gx < IMG)
      v = qg[((size_t)(b * CHN + cbase + c) * IMG + gy) * IMG + gx];
    qflat[idx] = v;
  }
  for (int idx = tid; idx < NC * KT * KT; idx += NTHR) {
    const int c = idx / (KT * KT);
    const int rem = idx - c * (KT * KT);
    const int r = rem / KT, col = rem - r * KT;
    const int gy = Y0 + r - 5, gx = X0 + col - 5;
    float v = 0.f;
    if ((unsigned)gy < IMG && (unsigned)gx < IMG)
      v = kg[((size_t)(b * CHN + cbase + c) * IMG + gy) * IMG + gx];
    t.ks[c][r][col] = v;
  }
}

__device__ constexpr int di_lo_o(int OB, int d) {
  const int di = OB / 9 + d;
  return OB > di * 9 ? OB : di * 9;
}
__device__ constexpr int di_hi_o(int OB, int ON, int d) {
  const int di = OB / 9 + d;
  return (OB + ON) < (di * 9 + 9) ? (OB + ON) : (di * 9 + 9);
}
__device__ constexpr bool h_needed(int OB, int ON, int d, int h) {
  const int lo = di_lo_o(OB, d), hi = di_hi_o(OB, ON, d);
  if (lo >= hi) return false;
  const int di = OB / 9 + d;
  const int clo = lo - di * 9, chi = (hi - 1 - di * 9) + 3;
  return (4 * h <= chi) && (4 * h + 3 >= clo);
}

// One di row's contribution. acc passed by reference but every caller is
// force-inlined, so SROA sees constant indices only -> registers.
template <int OB, int ON, int d>
__device__ AI void do_row(const Tiles& t, int c, int py, int xg4,
                          float qa0, float qa1, float qa2, float qa3,
                          float (&acc)[ON * 4]) {
  if constexpr (di_lo_o(OB, d) < di_hi_o(OB, ON, d)) {
    constexpr int DI0 = OB / 9;
    float kd[12];  // only ever indexed with compile-time constants
    if constexpr (h_needed(OB, ON, d, 0)) {
      const float4 v = *(const float4*)&t.ks[c][py + DI0 + d][xg4 + 0];
      kd[0] = v.x; kd[1] = v.y; kd[2] = v.z; kd[3] = v.w;
    }
    if constexpr (h_needed(OB, ON, d, 1)) {
      const float4 v = *(const float4*)&t.ks[c][py + DI0 + d][xg4 + 4];
      kd[4] = v.x; kd[5] = v.y; kd[6] = v.z; kd[7] = v.w;
    }
    if constexpr (h_needed(OB, ON, d, 2)) {
      const float4 v = *(const float4*)&t.ks[c][py + DI0 + d][xg4 + 8];
      kd[8] = v.x; kd[9] = v.y; kd[10] = v.z; kd[11] = v.w;
    }
#pragma unroll
    for (int oi = 0; oi < ON; ++oi) {
      if ((OB + oi) / 9 == DI0 + d) {            // constant-folded after unroll
        const int dj = (OB + oi) - ((OB + oi) / 9) * 9;
        acc[oi * 4 + 0] = __builtin_fmaf(qa0, kd[dj + 0], acc[oi * 4 + 0]);
        acc[oi * 4 + 1] = __builtin_fmaf(qa1, kd[dj + 1], acc[oi * 4 + 1]);
        acc[oi * 4 + 2] = __builtin_fmaf(qa2, kd[dj + 2], acc[oi * 4 + 2]);
        acc[oi * 4 + 3] = __builtin_fmaf(qa3, kd[dj + 3], acc[oi * 4 + 3]);
      }
    }
  }
}

template <int OB, int ON>
__device__ AI void run(const float* __restrict__ qg, const float* __restrict__ kg,
                       float* __restrict__ out, Tiles& t,
                       int b, int cbase0, int X0, int Y0, int tid, int lane) {
  const int xg  = lane & 3;    // 4 x-groups of 4 points = 16 cols
  const int py  = lane >> 2;   // 16 rows
  const int xg4 = xg * 4;

  float acc[ON * 4];
#pragma unroll
  for (int i = 0; i < ON * 4; ++i) acc[i] = 0.f;

  for (int cb = 0; cb < NCB; ++cb) {
    __syncthreads();                       // barrier #1 (matched across waves)
    stage(qg, kg, t, cbase0 + cb * NC, b, X0, Y0, tid);
    __syncthreads();                       // barrier #2
#pragma unroll 2
    for (int c = 0; c < NC; ++c) {
      const float4 qv = *(const float4*)&t.qs[c][py][xg4];
      do_row<OB, ON, 0>(t, c, py, xg4, qv.x, qv.y, qv.z, qv.w, acc);
      do_row<OB, ON, 1>(t, c, py, xg4, qv.x, qv.y, qv.z, qv.w, acc);
      do_row<OB, ON, 2>(t, c, py, xg4, qv.x, qv.y, qv.z, qv.w, acc);
    }
  }

  // Epilogue: 3x3 box sum entirely with shuffles (no LDS, no barriers).
  const int srcx = (xg < 3) ? (lane + 1) : lane;   // xg==3 values unused
  const int gy   = Y0 + py;
  const bool rowok = (py < OTILE) && (gy < IMG);
  float* obase = out + ((size_t)b * 81 * IMG + gy) * IMG + X0;
#pragma unroll
  for (int oi = 0; oi < ON; ++oi) {
    const float a0 = acc[oi * 4 + 0], a1 = acc[oi * 4 + 1];
    const float a2 = acc[oi * 4 + 2], a3 = acc[oi * 4 + 3];
    const float a0n = __shfl(a0, srcx);
    const float a1n = __shfl(a1, srcx);
    float s0 = a0 + a1 + a2;
    float s1 = a1 + a2 + a3;
    float s2 = a2 + a3 + a0n;
    float s3 = a3 + a0n + a1n;
    s0 += __shfl_down(s0, 4) + __shfl_down(s0, 8);
    s1 += __shfl_down(s1, 4) + __shfl_down(s1, 8);
    s2 += __shfl_down(s2, 4) + __shfl_down(s2, 8);
    s3 += __shfl_down(s3, 4) + __shfl_down(s3, 8);
    if (rowok) {
      const int o = OB + oi;
      float* orow = obase + (size_t)o * IMG * IMG;
      if (xg4 + 0 < OTILE && X0 + xg4 + 0 < IMG) atomicAdd(&orow[xg4 + 0], s0);
      if (xg4 + 1 < OTILE && X0 + xg4 + 1 < IMG) atomicAdd(&orow[xg4 + 1], s1);
      if (xg4 + 2 < OTILE && X0 + xg4 + 2 < IMG) atomicAdd(&orow[xg4 + 2], s2);
      if (xg4 + 3 < OTILE && X0 + xg4 + 3 < IMG) atomicAdd(&orow[xg4 + 3], s3);
    }
  }
}

__global__ __launch_bounds__(NTHR, 1) void spatial_corr_kernel(const float* __restrict__ q,
                                                               const float* __restrict__ k,
                                                               float* __restrict__ out) {
  __shared__ Tiles t;
  const int tid  = threadIdx.x;
  const int w    = tid >> 6;
  const int lane = tid & 63;
  const int b      = blockIdx.z >> 1;
  const int cbase0 = (blockIdx.z & 1) * CHALF;
  const int X0 = blockIdx.x * OTILE;
  const int Y0 = blockIdx.y * OTILE;
  // 8 waves x (11,10,...,10) offsets; every window spans exactly 2 di rows.
  if (w == 0)      run<0,  11>(q, k, out, t, b, cbase0, X0, Y0, tid, lane);
  else if (w == 1) run<11, 10>(q, k, out, t, b, cbase0, X0, Y0, tid, lane);
  else if (w == 2) run<21, 10>(q, k, out, t, b, cbase0, X0, Y0, tid, lane);
  else if (w == 3) run<31, 10>(q, k, out, t, b, cbase0, X0, Y0, tid, lane);
  else if (w == 4) run<41, 10>(q, k, out, t, b, cbase0, X0, Y0, tid, lane);
  else if (w == 5) run<51, 10>(q, k, out, t, b, cbase0, X0, Y0, tid, lane);
  else if (w == 6) run<61, 10>(q, k, out, t, b, cbase0, X0, Y0, tid, lane);
  else             run<71, 10>(q, k, out, t, b, cbase0, X0, Y0, tid, lane);
}

extern "C" void kernel_launch(void* const* d_in, const int* in_sizes, int n_in,
                              void* d_out, int out_size, void* d_ws, size_t ws_size,
                              hipStream_t stream) {
  const float* q = (const float*)d_in[0];
  const float* k = (const float*)d_in[1];
  // d_in[2] (value) is unused by the reference output.
  float* out = (float*)d_out;
  hipMemsetAsync(out, 0, (size_t)out_size * sizeof(float), stream);
  dim3 grid(7, 7, BATCH * 2);   // x-tiles, y-tiles, batch x channel-half
  dim3 block(NTHR);
  hipLaunchKernelGGL(spatial_corr_kernel, grid, block, 0, stream, q, k, out);
}